// Round 2
// baseline (1200.846 us; speedup 1.0000x reference)
//
#include <hip/hip_runtime.h>

#define N_ATOMS 131072
#define N_TYPES 256
#define D 64
#define CAP 1024   // per-type capacity; counts ~Binomial(131072,1/256): mean 512, sd 22.6 -> 22 sigma
#define BPT 2      // blocks per type in apply
#define DCH 128    // atoms per wave chunk (2 per lane)

// ---------------------------------------------------------------------------
// Pass 1: counting-sort atoms by type into fixed-capacity buckets.
// ---------------------------------------------------------------------------
__global__ __launch_bounds__(256) void scatter_kernel(
    const int* __restrict__ types, int* __restrict__ cursor, int* __restrict__ bucket)
{
    __shared__ int lhist[N_TYPES];
    __shared__ int lbase[N_TYPES];
    __shared__ int lcur[N_TYPES];
    const int tid = threadIdx.x;
    lhist[tid] = 0;
    __syncthreads();

    const int a0 = blockIdx.x * 512 + tid;
    const int a1 = a0 + 256;
    const int t0 = types[a0];
    const int t1 = types[a1];
    atomicAdd(&lhist[t0], 1);
    atomicAdd(&lhist[t1], 1);
    __syncthreads();

    const int cnt = lhist[tid];
    if (cnt > 0) lbase[tid] = atomicAdd(&cursor[tid], cnt);
    lcur[tid] = 0;
    __syncthreads();

    int p0 = atomicAdd(&lcur[t0], 1);
    int q0 = lbase[t0] + p0;
    if (q0 < CAP) bucket[t0 * CAP + q0] = a0;
    int p1 = atomicAdd(&lcur[t1], 1);
    int q1 = lbase[t1] + p1;
    if (q1 < CAP) bucket[t1 * CAP + q1] = a1;
}

// ---------------------------------------------------------------------------
// Pass 2: per-type apply. W[t],b[t] staged in LDS (broadcast ds_read_b128 is
// conflict-free). 2 atoms per lane: one W float4 read feeds 8 FMAs, so the
// LDS pipe (~6 cyc/b128) sits under the 16 cyc of FMA it feeds. Both x rows
// resident in VGPRs (~190) — loaded once, reused across all 4 oc passes.
// TLP is structurally ~2 waves/SIMD (2048 waves total); ILP carries.
// ---------------------------------------------------------------------------
__device__ __forceinline__ float fast_tanh(float v)
{
    float e = __expf(2.0f * v);
    return 1.0f - __fdividef(2.0f, e + 1.0f);
}

__global__ __launch_bounds__(256, 2) void apply_kernel(
    const float* __restrict__ x, const float* __restrict__ W,
    const float* __restrict__ b, const int* __restrict__ bucket,
    const int* __restrict__ cursor, float* __restrict__ out)
{
    __shared__ float Wl[D * D];   // 16 KB
    __shared__ float bl[D];

    const int t = blockIdx.y;     // type: uniform across block
    const int j = blockIdx.x;     // 0..BPT-1

    // cooperative stage: 1024 float4 over 256 threads
    {
        const float4* Wg4 = (const float4*)(W + (size_t)t * (D * D));
        float4* Wl4 = (float4*)Wl;
#pragma unroll
        for (int k = 0; k < 4; ++k)
            Wl4[threadIdx.x + 256 * k] = Wg4[threadIdx.x + 256 * k];
        if (threadIdx.x < D) bl[threadIdx.x] = b[(size_t)t * D + threadIdx.x];
    }
    int n = cursor[t];
    if (n > CAP) n = CAP;
    __syncthreads();

    const int wave = threadIdx.x >> 6;
    const int lane = threadIdx.x & 63;
    const int* bk = bucket + (size_t)t * CAP;

    // d = wave*BPT + j: for n<=512 both blocks keep 2 waves busy each
    for (int d = wave * BPT + j; d * DCH < n; d += 4 * BPT) {
        const int r0 = d * DCH + lane;
        const int r1 = r0 + 64;
        const bool vA = (r0 < n);
        const bool vB = (r1 < n);
        const int ia = bk[vA ? r0 : 0];   // guard: bucket beyond n is poison
        const int ib = bk[vB ? r1 : 0];

        float4 xa4[16], xb4[16];          // both x rows resident: 128 VGPRs
        {
            const float4* xga = (const float4*)(x + (size_t)ia * D);
            const float4* xgb = (const float4*)(x + (size_t)ib * D);
#pragma unroll
            for (int i = 0; i < 16; ++i) { xa4[i] = xga[i]; xb4[i] = xgb[i]; }
        }

#pragma unroll 1
        for (int oc = 0; oc < 4; ++oc) {  // 4 chunks of 16 outputs
            float accA[16], accB[16];
#pragma unroll
            for (int oo = 0; oo < 16; ++oo) {
                float bb = bl[oc * 16 + oo];
                accA[oo] = bb; accB[oo] = bb;
            }
#pragma unroll
            for (int oo = 0; oo < 16; ++oo) {
                const float4* wr = (const float4*)(Wl + (size_t)(oc * 16 + oo) * D);
#pragma unroll
                for (int q = 0; q < 16; ++q) {
                    float4 w4 = wr[q];        // broadcast ds_read_b128 -> 8 FMAs
                    float4 a4 = xa4[q];
                    float4 b4 = xb4[q];
                    accA[oo] = fmaf(w4.x, a4.x, accA[oo]);
                    accA[oo] = fmaf(w4.y, a4.y, accA[oo]);
                    accA[oo] = fmaf(w4.z, a4.z, accA[oo]);
                    accA[oo] = fmaf(w4.w, a4.w, accA[oo]);
                    accB[oo] = fmaf(w4.x, b4.x, accB[oo]);
                    accB[oo] = fmaf(w4.y, b4.y, accB[oo]);
                    accB[oo] = fmaf(w4.z, b4.z, accB[oo]);
                    accB[oo] = fmaf(w4.w, b4.w, accB[oo]);
                }
            }
            if (vA) {
                float4* ya = (float4*)(out + (size_t)ia * D + oc * 16);
#pragma unroll
                for (int q = 0; q < 4; ++q) {
                    float4 o4;
                    o4.x = fast_tanh(accA[4 * q + 0]);
                    o4.y = fast_tanh(accA[4 * q + 1]);
                    o4.z = fast_tanh(accA[4 * q + 2]);
                    o4.w = fast_tanh(accA[4 * q + 3]);
                    ya[q] = o4;
                }
            }
            if (vB) {
                float4* yb = (float4*)(out + (size_t)ib * D + oc * 16);
#pragma unroll
                for (int q = 0; q < 4; ++q) {
                    float4 o4;
                    o4.x = fast_tanh(accB[4 * q + 0]);
                    o4.y = fast_tanh(accB[4 * q + 1]);
                    o4.z = fast_tanh(accB[4 * q + 2]);
                    o4.w = fast_tanh(accB[4 * q + 3]);
                    yb[q] = o4;
                }
            }
        }
    }
}

extern "C" void kernel_launch(void* const* d_in, const int* in_sizes, int n_in,
                              void* d_out, int out_size, void* d_ws, size_t ws_size,
                              hipStream_t stream)
{
    const float* x     = (const float*)d_in[0];
    const int*   types = (const int*)  d_in[1];
    const float* W     = (const float*)d_in[2];
    const float* b     = (const float*)d_in[3];
    float*       out   = (float*)d_out;

    int* cursor = (int*)d_ws;
    int* bucket = (int*)((char*)d_ws + 1024);

    hipMemsetAsync(cursor, 0, N_TYPES * sizeof(int), stream);
    scatter_kernel<<<dim3(N_ATOMS / 512), dim3(256), 0, stream>>>(types, cursor, bucket);
    apply_kernel<<<dim3(BPT, N_TYPES), dim3(256), 0, stream>>>(x, W, b, bucket, cursor, out);
}

// Round 3
// 203.674 us; speedup vs baseline: 5.8959x; 5.8959x over previous
//
#include <hip/hip_runtime.h>

#define N_ATOMS 131072
#define N_TYPES 256
#define D 64
#define CAP 1024   // per-type capacity; counts ~Binomial(131072,1/256): mean 512, sd 22.6 -> 22 sigma

// ---------------------------------------------------------------------------
// Pass 1: counting-sort atoms by type into fixed-capacity buckets.
// ---------------------------------------------------------------------------
__global__ __launch_bounds__(256) void scatter_kernel(
    const int* __restrict__ types, int* __restrict__ cursor, int* __restrict__ bucket)
{
    __shared__ int lhist[N_TYPES];
    __shared__ int lbase[N_TYPES];
    __shared__ int lcur[N_TYPES];
    const int tid = threadIdx.x;
    lhist[tid] = 0;
    __syncthreads();

    const int a0 = blockIdx.x * 512 + tid;
    const int a1 = a0 + 256;
    const int t0 = types[a0];
    const int t1 = types[a1];
    atomicAdd(&lhist[t0], 1);
    atomicAdd(&lhist[t1], 1);
    __syncthreads();

    const int cnt = lhist[tid];
    if (cnt > 0) lbase[tid] = atomicAdd(&cursor[tid], cnt);
    lcur[tid] = 0;
    __syncthreads();

    int p0 = atomicAdd(&lcur[t0], 1);
    int q0 = lbase[t0] + p0;
    if (q0 < CAP) bucket[t0 * CAP + q0] = a0;
    int p1 = atomicAdd(&lcur[t1], 1);
    int q1 = lbase[t1] + p1;
    if (q1 < CAP) bucket[t1 * CAP + q1] = a1;
}

// ---------------------------------------------------------------------------
// Pass 2: one 512-thread block per type (W staged to LDS ONCE per type ->
// 4 MB total W fetch). Lane = atom; x row resident in 64 VGPRs, loaded once
// and reused by all 4 fully-unrolled output chunks (no serial oc loop ->
// nothing to rematerialize, peak live ~100 VGPR < 128 budget -> no spill).
// W reads are wave-uniform broadcast ds_read_b128 (conflict-free by the
// same-address rule); 4 fp32 FMAs (8 cyc) per read.
// ---------------------------------------------------------------------------
__device__ __forceinline__ float fast_tanh(float v)
{
    float e = __expf(2.0f * v);
    return 1.0f - __fdividef(2.0f, e + 1.0f);
}

__global__ __launch_bounds__(512, 1) void apply_kernel(
    const float* __restrict__ x, const float* __restrict__ W,
    const float* __restrict__ b, const int* __restrict__ bucket,
    const int* __restrict__ cursor, float* __restrict__ out)
{
    __shared__ float Wl[D * D];   // 16 KB
    __shared__ float bl[D];

    const int t = blockIdx.x;     // type: uniform across block

    // cooperative stage: 1024 float4 over 512 threads
    {
        const float4* Wg4 = (const float4*)(W + (size_t)t * (D * D));
        float4* Wl4 = (float4*)Wl;
#pragma unroll
        for (int k = 0; k < 2; ++k)
            Wl4[threadIdx.x + 512 * k] = Wg4[threadIdx.x + 512 * k];
        if (threadIdx.x < D) bl[threadIdx.x] = b[(size_t)t * D + threadIdx.x];
    }
    int n = cursor[t];
    if (n > CAP) n = CAP;
    __syncthreads();

    const int wave = threadIdx.x >> 6;
    const int lane = threadIdx.x & 63;
    const int* bk = bucket + (size_t)t * CAP;

    // 8 waves cover 512 atoms per pass; types with n>512 take a 2nd pass
    for (int d = wave; d * 64 < n; d += 8) {
        const int r = d * 64 + lane;
        const bool valid = (r < n);
        const int atom = bk[valid ? r : 0];   // n>=1 whenever loop entered

        // x row resident: 16 global_load_dwordx4, per-lane contiguous 256 B
        float4 xv[16];
        {
            const float4* xr = (const float4*)(x + (size_t)atom * D);
#pragma unroll
            for (int i = 0; i < 16; ++i) xv[i] = xr[i];
        }
        float* yo = out + (size_t)atom * D;

#pragma unroll
        for (int oc = 0; oc < 4; ++oc) {      // fully unrolled: 4 x 16 outputs
            float acc[16];
#pragma unroll
            for (int oo = 0; oo < 16; ++oo) acc[oo] = bl[oc * 16 + oo];

#pragma unroll
            for (int oo = 0; oo < 16; ++oo) {
                const float4* wr = (const float4*)(Wl + (size_t)(oc * 16 + oo) * D);
#pragma unroll
                for (int q = 0; q < 16; ++q) {
                    float4 w4 = wr[q];        // broadcast ds_read_b128
                    float4 a4 = xv[q];
                    acc[oo] = fmaf(w4.x, a4.x, acc[oo]);
                    acc[oo] = fmaf(w4.y, a4.y, acc[oo]);
                    acc[oo] = fmaf(w4.z, a4.z, acc[oo]);
                    acc[oo] = fmaf(w4.w, a4.w, acc[oo]);
                }
            }

            if (valid) {
                float4* y4 = (float4*)(yo + oc * 16);
#pragma unroll
                for (int qq = 0; qq < 4; ++qq) {
                    float4 o4;
                    o4.x = fast_tanh(acc[4 * qq + 0]);
                    o4.y = fast_tanh(acc[4 * qq + 1]);
                    o4.z = fast_tanh(acc[4 * qq + 2]);
                    o4.w = fast_tanh(acc[4 * qq + 3]);
                    y4[qq] = o4;
                }
            }
        }
    }
}

extern "C" void kernel_launch(void* const* d_in, const int* in_sizes, int n_in,
                              void* d_out, int out_size, void* d_ws, size_t ws_size,
                              hipStream_t stream)
{
    const float* x     = (const float*)d_in[0];
    const int*   types = (const int*)  d_in[1];
    const float* W     = (const float*)d_in[2];
    const float* b     = (const float*)d_in[3];
    float*       out   = (float*)d_out;

    int* cursor = (int*)d_ws;
    int* bucket = (int*)((char*)d_ws + 1024);

    hipMemsetAsync(cursor, 0, N_TYPES * sizeof(int), stream);
    scatter_kernel<<<dim3(N_ATOMS / 512), dim3(256), 0, stream>>>(types, cursor, bucket);
    apply_kernel<<<dim3(N_TYPES), dim3(512), 0, stream>>>(x, W, b, bucket, cursor, out);
}

// Round 4
// 112.716 us; speedup vs baseline: 10.6537x; 1.8070x over previous
//
#include <hip/hip_runtime.h>

#define N_ATOMS 131072
#define N_TYPES 256
#define D 64
#define CAP 1024   // per-type capacity; counts ~Binomial(131072,1/256): mean 512, sd 22.6 -> 22 sigma
#define BPT 4      // blocks per type in apply

using sfrag = __attribute__((ext_vector_type(8))) short;   // 8 bf16 (4 VGPRs)
using ffrag = __attribute__((ext_vector_type(4))) float;   // 4 fp32 acc

__device__ __forceinline__ short f2bf(float f)
{
    union { float f; unsigned u; } v; v.f = f;
    unsigned r = v.u + 0x7FFFu + ((v.u >> 16) & 1u);   // round-to-nearest-even
    return (short)(r >> 16);
}

__device__ __forceinline__ float fast_tanh(float v)
{
    float e = __expf(2.0f * v);
    return 1.0f - __fdividef(2.0f, e + 1.0f);
}

// ---------------------------------------------------------------------------
// Pass 1: counting-sort atoms by type into fixed-capacity buckets.
// ---------------------------------------------------------------------------
__global__ __launch_bounds__(256) void scatter_kernel(
    const int* __restrict__ types, int* __restrict__ cursor, int* __restrict__ bucket)
{
    __shared__ int lhist[N_TYPES];
    __shared__ int lbase[N_TYPES];
    __shared__ int lcur[N_TYPES];
    const int tid = threadIdx.x;
    lhist[tid] = 0;
    __syncthreads();

    const int a0 = blockIdx.x * 512 + tid;
    const int a1 = a0 + 256;
    const int t0 = types[a0];
    const int t1 = types[a1];
    atomicAdd(&lhist[t0], 1);
    atomicAdd(&lhist[t1], 1);
    __syncthreads();

    const int cnt = lhist[tid];
    if (cnt > 0) lbase[tid] = atomicAdd(&cursor[tid], cnt);
    lcur[tid] = 0;
    __syncthreads();

    int p0 = atomicAdd(&lcur[t0], 1);
    int q0 = lbase[t0] + p0;
    if (q0 < CAP) bucket[t0 * CAP + q0] = a0;
    int p1 = atomicAdd(&lcur[t1], 1);
    int q1 = lbase[t1] + p1;
    if (q1 < CAP) bucket[t1 * CAP + q1] = a1;
}

// ---------------------------------------------------------------------------
// Pass 2: MFMA bf16, zero LDS. Per block: type t (uniform). B-frags = W[t]
// loaded ONCE into 32 VGPRs directly in fragment layout (lane holds 8
// contiguous k of row n=lane&15 -> contiguous global read). Per 16-atom
// group: A-frags gathered directly in fragment layout (lane holds 8
// contiguous k of atom row m=lane&15), 8 MFMAs, bias+tanh epilogue writes
// each atom's full 256 B row within one epilogue (no partial-line churn).
// fp32 accumulate; only error is bf16 input rounding (~0.01 << 0.02 thr).
// ---------------------------------------------------------------------------
__global__ __launch_bounds__(256, 4) void apply_kernel(
    const float* __restrict__ x, const float* __restrict__ W,
    const float* __restrict__ b, const int* __restrict__ bucket,
    const int* __restrict__ cursor, float* __restrict__ out)
{
    const int t = blockIdx.y;      // type: uniform across block
    const int j = blockIdx.x;      // 0..BPT-1
    int n = cursor[t];
    if (n > CAP) n = CAP;

    const int wave = threadIdx.x >> 6;
    const int lane = threadIdx.x & 63;
    const int c = lane & 15;       // A: atom-in-tile | B/CD: output column
    const int q = lane >> 4;       // k-quad / CD row group

    const int*   bk = bucket + (size_t)t * CAP;
    const float* Wt = W + (size_t)t * (D * D);

    // B-frags: B[k][n] = W[n][k]; lane holds W[nt*16+c][ks*32+q*8+jj], jj=0..7
    sfrag Bf[4][2];
#pragma unroll
    for (int nt = 0; nt < 4; ++nt) {
#pragma unroll
        for (int ks = 0; ks < 2; ++ks) {
            const float4* wr = (const float4*)(Wt + (size_t)(nt * 16 + c) * D + ks * 32 + q * 8);
            float4 w0 = wr[0], w1 = wr[1];
            sfrag f;
            f[0] = f2bf(w0.x); f[1] = f2bf(w0.y); f[2] = f2bf(w0.z); f[3] = f2bf(w0.w);
            f[4] = f2bf(w1.x); f[5] = f2bf(w1.y); f[6] = f2bf(w1.z); f[7] = f2bf(w1.w);
            Bf[nt][ks] = f;
        }
    }
    float bias[4];
#pragma unroll
    for (int nt = 0; nt < 4; ++nt) bias[nt] = b[(size_t)t * D + nt * 16 + c];

    // groups of 16 atoms; 16 waves stride the (up to 64) groups of this type
    for (int g = j * 4 + wave; g * 16 < n; g += BPT * 4) {
        const int base = g * 16;

        // A gather: atom row m = c, k-segment q*8 (ks0) and 32+q*8 (ks1)
        int ridx = base + c;
        if (ridx >= n) ridx = n - 1;        // duplicate last row; stores guarded
        const int aidx = bk[ridx];
        const float4* xr = (const float4*)x + (size_t)aidx * 16 + q * 2;
        float4 x0 = xr[0], x1 = xr[1];      // k = q*8 .. q*8+7
        float4 x2 = xr[8], x3 = xr[9];      // k = 32+q*8 ..
        sfrag A0, A1;
        A0[0] = f2bf(x0.x); A0[1] = f2bf(x0.y); A0[2] = f2bf(x0.z); A0[3] = f2bf(x0.w);
        A0[4] = f2bf(x1.x); A0[5] = f2bf(x1.y); A0[6] = f2bf(x1.z); A0[7] = f2bf(x1.w);
        A1[0] = f2bf(x2.x); A1[1] = f2bf(x2.y); A1[2] = f2bf(x2.z); A1[3] = f2bf(x2.w);
        A1[4] = f2bf(x3.x); A1[5] = f2bf(x3.y); A1[6] = f2bf(x3.z); A1[7] = f2bf(x3.w);

        // C/D rows: atom = base + q*4 + r
        int  oat[4]; bool ov[4];
#pragma unroll
        for (int r = 0; r < 4; ++r) {
            int arow = base + q * 4 + r;
            ov[r]  = (arow < n);
            oat[r] = bk[ov[r] ? arow : 0];
        }

#pragma unroll
        for (int nt = 0; nt < 4; ++nt) {
            ffrag acc = {0.f, 0.f, 0.f, 0.f};
            acc = __builtin_amdgcn_mfma_f32_16x16x32_bf16(A0, Bf[nt][0], acc, 0, 0, 0);
            acc = __builtin_amdgcn_mfma_f32_16x16x32_bf16(A1, Bf[nt][1], acc, 0, 0, 0);
#pragma unroll
            for (int r = 0; r < 4; ++r) {
                if (ov[r])
                    out[(size_t)oat[r] * D + nt * 16 + c] = fast_tanh(acc[r] + bias[nt]);
            }
        }
    }
}

extern "C" void kernel_launch(void* const* d_in, const int* in_sizes, int n_in,
                              void* d_out, int out_size, void* d_ws, size_t ws_size,
                              hipStream_t stream)
{
    const float* x     = (const float*)d_in[0];
    const int*   types = (const int*)  d_in[1];
    const float* W     = (const float*)d_in[2];
    const float* b     = (const float*)d_in[3];
    float*       out   = (float*)d_out;

    int* cursor = (int*)d_ws;
    int* bucket = (int*)((char*)d_ws + 1024);

    hipMemsetAsync(cursor, 0, N_TYPES * sizeof(int), stream);
    scatter_kernel<<<dim3(N_ATOMS / 512), dim3(256), 0, stream>>>(types, cursor, bucket);
    apply_kernel<<<dim3(BPT, N_TYPES), dim3(256), 0, stream>>>(x, W, b, bucket, cursor, out);
}

// Round 5
// 109.589 us; speedup vs baseline: 10.9578x; 1.0285x over previous
//
#include <hip/hip_runtime.h>

#define N_ATOMS 131072
#define N_TYPES 256
#define D 64
#define CAP 1024   // per-type capacity; counts ~Binomial(131072,1/256): mean 512, sd 22.6 -> 22 sigma
#define BPT 4      // blocks per type in apply

using sfrag = __attribute__((ext_vector_type(8))) short;   // 8 bf16 (4 VGPRs)
using ffrag = __attribute__((ext_vector_type(4))) float;   // 4 fp32 acc

__device__ __forceinline__ short f2bf(float f)
{
    union { float f; unsigned u; } v; v.f = f;
    unsigned r = v.u + 0x7FFFu + ((v.u >> 16) & 1u);   // round-to-nearest-even
    return (short)(r >> 16);
}

__device__ __forceinline__ float fast_tanh(float v)
{
    float e = __expf(2.0f * v);
    return 1.0f - __fdividef(2.0f, e + 1.0f);
}

// ---------------------------------------------------------------------------
// Pass 1: counting-sort atoms by type into fixed-capacity buckets.
// ---------------------------------------------------------------------------
__global__ __launch_bounds__(256) void scatter_kernel(
    const int* __restrict__ types, int* __restrict__ cursor, int* __restrict__ bucket)
{
    __shared__ int lhist[N_TYPES];
    __shared__ int lbase[N_TYPES];
    __shared__ int lcur[N_TYPES];
    const int tid = threadIdx.x;
    lhist[tid] = 0;
    __syncthreads();

    const int a0 = blockIdx.x * 512 + tid;
    const int a1 = a0 + 256;
    const int t0 = types[a0];
    const int t1 = types[a1];
    atomicAdd(&lhist[t0], 1);
    atomicAdd(&lhist[t1], 1);
    __syncthreads();

    const int cnt = lhist[tid];
    if (cnt > 0) lbase[tid] = atomicAdd(&cursor[tid], cnt);
    lcur[tid] = 0;
    __syncthreads();

    int p0 = atomicAdd(&lcur[t0], 1);
    int q0 = lbase[t0] + p0;
    if (q0 < CAP) bucket[t0 * CAP + q0] = a0;
    int p1 = atomicAdd(&lcur[t1], 1);
    int q1 = lbase[t1] + p1;
    if (q1 < CAP) bucket[t1 * CAP + q1] = a1;
}

// ---------------------------------------------------------------------------
// Pass 2: MFMA bf16, zero LDS, 1-deep software pipeline.
// Per block: type t (uniform); B-frags = W[t] in 32 VGPRs, loaded once.
// Per 16-atom group: prefetch next group's bucket idx + x while computing
// current (overlaps the ~1200cyc bucket->x chain with MFMA/tanh). Epilogue
// row indices come from __shfl of the A-gather indices (lanes 0..15 hold
// bk[base+0..15]) -- no redundant bucket loads.
// ---------------------------------------------------------------------------
__global__ __launch_bounds__(256, 4) void apply_kernel(
    const float* __restrict__ x, const float* __restrict__ W,
    const float* __restrict__ b, const int* __restrict__ bucket,
    const int* __restrict__ cursor, float* __restrict__ out)
{
    const int t = blockIdx.y;      // type: uniform across block
    const int j = blockIdx.x;      // 0..BPT-1
    int n = cursor[t];
    if (n > CAP) n = CAP;

    const int wave = threadIdx.x >> 6;
    const int lane = threadIdx.x & 63;
    const int c = lane & 15;       // A: atom-in-tile | B/CD: output column
    const int q = lane >> 4;       // k-quad / CD row group

    const int*   bk = bucket + (size_t)t * CAP;
    const float* Wt = W + (size_t)t * (D * D);

    // B-frags: B[k][n] = W[n][k]; lane holds W[nt*16+c][ks*32+q*8+jj], jj=0..7
    sfrag Bf[4][2];
#pragma unroll
    for (int nt = 0; nt < 4; ++nt) {
#pragma unroll
        for (int ks = 0; ks < 2; ++ks) {
            const float4* wr = (const float4*)(Wt + (size_t)(nt * 16 + c) * D + ks * 32 + q * 8);
            float4 w0 = wr[0], w1 = wr[1];
            sfrag f;
            f[0] = f2bf(w0.x); f[1] = f2bf(w0.y); f[2] = f2bf(w0.z); f[3] = f2bf(w0.w);
            f[4] = f2bf(w1.x); f[5] = f2bf(w1.y); f[6] = f2bf(w1.z); f[7] = f2bf(w1.w);
            Bf[nt][ks] = f;
        }
    }
    float bias[4];
#pragma unroll
    for (int nt = 0; nt < 4; ++nt) bias[nt] = b[(size_t)t * D + nt * 16 + c];

    const int stride = BPT * 4;    // 16 waves cover the type's groups
    int g = j * 4 + wave;
    if (g * 16 >= n) return;

    // ---- stage 0 load: bucket idx + x row (raw fp32; cvt deferred to use)
    int aidx; float4 x0, x1, x2, x3;
    {
        int ridx = g * 16 + c;
        if (ridx >= n) ridx = n - 1;          // duplicate last row; stores guarded
        aidx = bk[ridx];
        const float4* xr = (const float4*)x + (size_t)aidx * 16 + q * 2;
        x0 = xr[0]; x1 = xr[1]; x2 = xr[8]; x3 = xr[9];
    }

    while (true) {
        const int gn = g + stride;
        const bool more = (gn * 16 < n);      // n uniform per block: no divergence

        // ---- prefetch next stage (issued before current compute)
        int naidx = 0; float4 nx0, nx1, nx2, nx3;
        if (more) {
            int ridx = gn * 16 + c;
            if (ridx >= n) ridx = n - 1;
            naidx = bk[ridx];
            const float4* xr = (const float4*)x + (size_t)naidx * 16 + q * 2;
            nx0 = xr[0]; nx1 = xr[1]; nx2 = xr[8]; nx3 = xr[9];
        }

        // ---- compute current group
        sfrag A0, A1;
        A0[0] = f2bf(x0.x); A0[1] = f2bf(x0.y); A0[2] = f2bf(x0.z); A0[3] = f2bf(x0.w);
        A0[4] = f2bf(x1.x); A0[5] = f2bf(x1.y); A0[6] = f2bf(x1.z); A0[7] = f2bf(x1.w);
        A1[0] = f2bf(x2.x); A1[1] = f2bf(x2.y); A1[2] = f2bf(x2.z); A1[3] = f2bf(x2.w);
        A1[4] = f2bf(x3.x); A1[5] = f2bf(x3.y); A1[6] = f2bf(x3.z); A1[7] = f2bf(x3.w);

        const int base = g * 16;
        int  oat[4]; bool ov[4];
#pragma unroll
        for (int r = 0; r < 4; ++r) {
            ov[r]  = (base + q * 4 + r) < n;
            oat[r] = __shfl(aidx, q * 4 + r, 64);   // lanes 0..15 hold bk[base+0..15]
        }

#pragma unroll
        for (int nt = 0; nt < 4; ++nt) {
            ffrag acc = {0.f, 0.f, 0.f, 0.f};
            acc = __builtin_amdgcn_mfma_f32_16x16x32_bf16(A0, Bf[nt][0], acc, 0, 0, 0);
            acc = __builtin_amdgcn_mfma_f32_16x16x32_bf16(A1, Bf[nt][1], acc, 0, 0, 0);
#pragma unroll
            for (int r = 0; r < 4; ++r) {
                if (ov[r])
                    out[(size_t)oat[r] * D + nt * 16 + c] = fast_tanh(acc[r] + bias[nt]);
            }
        }

        if (!more) break;
        g = gn; aidx = naidx;
        x0 = nx0; x1 = nx1; x2 = nx2; x3 = nx3;
    }
}

extern "C" void kernel_launch(void* const* d_in, const int* in_sizes, int n_in,
                              void* d_out, int out_size, void* d_ws, size_t ws_size,
                              hipStream_t stream)
{
    const float* x     = (const float*)d_in[0];
    const int*   types = (const int*)  d_in[1];
    const float* W     = (const float*)d_in[2];
    const float* b     = (const float*)d_in[3];
    float*       out   = (float*)d_out;

    int* cursor = (int*)d_ws;
    int* bucket = (int*)((char*)d_ws + 1024);

    hipMemsetAsync(cursor, 0, N_TYPES * sizeof(int), stream);
    scatter_kernel<<<dim3(N_ATOMS / 512), dim3(256), 0, stream>>>(types, cursor, bucket);
    apply_kernel<<<dim3(BPT, N_TYPES), dim3(256), 0, stream>>>(x, W, b, bucket, cursor, out);
}

// Round 6
// 106.181 us; speedup vs baseline: 11.3094x; 1.0321x over previous
//
#include <hip/hip_runtime.h>

#define N_ATOMS 131072
#define N_TYPES 256
#define D 64
#define CAP 1024   // per-type capacity; counts ~Binomial(131072,1/256): mean 512, sd 22.6 -> 22 sigma
#define BPT 4      // blocks per type in apply

using sfrag = __attribute__((ext_vector_type(8))) short;   // 8 bf16 (4 VGPRs)
using ffrag = __attribute__((ext_vector_type(4))) float;   // 4 fp32 acc

__device__ __forceinline__ short f2bf(float f)
{
    union { float f; unsigned u; } v; v.f = f;
    unsigned r = v.u + 0x7FFFu + ((v.u >> 16) & 1u);   // round-to-nearest-even
    return (short)(r >> 16);
}

__device__ __forceinline__ float fast_tanh(float v)
{
    float e = __expf(2.0f * v);
    return 1.0f - __fdividef(2.0f, e + 1.0f);
}

// ---------------------------------------------------------------------------
// Pass 1: counting sort. 128 blocks x 256 thr x 4 atoms: 4x fewer blocks
// -> 4x fewer global cursor atomics (the serialization point: 256 counters
// live on only 16 cache lines). LDS-aggregated as before.
// ---------------------------------------------------------------------------
__global__ __launch_bounds__(256) void scatter_kernel(
    const int* __restrict__ types, int* __restrict__ cursor, int* __restrict__ bucket)
{
    __shared__ int lhist[N_TYPES];
    __shared__ int lbase[N_TYPES];
    __shared__ int lcur[N_TYPES];
    const int tid  = threadIdx.x;
    const int base = blockIdx.x * 1024;
    lhist[tid] = 0;
    __syncthreads();

    int ty[4];
#pragma unroll
    for (int k = 0; k < 4; ++k) ty[k] = types[base + k * 256 + tid];   // coalesced
#pragma unroll
    for (int k = 0; k < 4; ++k) atomicAdd(&lhist[ty[k]], 1);
    __syncthreads();

    const int cnt = lhist[tid];
    if (cnt > 0) lbase[tid] = atomicAdd(&cursor[tid], cnt);   // ~250/block, 128 blocks
    lcur[tid] = 0;
    __syncthreads();

#pragma unroll
    for (int k = 0; k < 4; ++k) {
        const int t = ty[k];
        const int p = atomicAdd(&lcur[t], 1);
        const int q = lbase[t] + p;
        if (q < CAP) bucket[t * CAP + q] = base + k * 256 + tid;
    }
}

// ---------------------------------------------------------------------------
// Pass 2: MFMA bf16, zero LDS, 1-deep pipeline. XCD-affine linear grid:
// block b -> t = b&255, j = b>>8, so a type's 4 blocks share b%8 (same XCD
// under round-robin dispatch) -> W[t] fetched into ONE L2 (W HBM 16->~5MB,
// B-frag startup becomes L2-hit for 3 of 4 blocks). Stage-0 bucket load
// issued before W loads (longest chain first).
// ---------------------------------------------------------------------------
__global__ __launch_bounds__(256, 4) void apply_kernel(
    const float* __restrict__ x, const float* __restrict__ W,
    const float* __restrict__ b, const int* __restrict__ bucket,
    const int* __restrict__ cursor, float* __restrict__ out)
{
    const int t = blockIdx.x & 255;    // type: uniform across block
    const int j = blockIdx.x >> 8;     // 0..BPT-1
    int n = cursor[t];
    if (n > CAP) n = CAP;

    const int wave = threadIdx.x >> 6;
    const int lane = threadIdx.x & 63;
    const int c = lane & 15;           // A: atom-in-tile | B/CD: output column
    const int q = lane >> 4;           // k-quad / CD row group

    const int*   bk = bucket + (size_t)t * CAP;
    const float* Wt = W + (size_t)t * (D * D);

    const int stride = BPT * 4;        // 16 waves cover the type's groups
    int g = j * 4 + wave;
    if (g * 16 >= n) return;

    // ---- stage-0 bucket index: head of the longest dependence chain
    int aidx;
    {
        int ridx = g * 16 + c;
        if (ridx >= n) ridx = n - 1;   // duplicate last row; stores guarded
        aidx = bk[ridx];
    }

    // ---- B-frags (independent; issue under the bucket-load shadow)
    // B[k][n] = W[n][k]; lane holds W[nt*16+c][ks*32+q*8+jj], jj=0..7
    sfrag Bf[4][2];
#pragma unroll
    for (int nt = 0; nt < 4; ++nt) {
#pragma unroll
        for (int ks = 0; ks < 2; ++ks) {
            const float4* wr = (const float4*)(Wt + (size_t)(nt * 16 + c) * D + ks * 32 + q * 8);
            float4 w0 = wr[0], w1 = wr[1];
            sfrag f;
            f[0] = f2bf(w0.x); f[1] = f2bf(w0.y); f[2] = f2bf(w0.z); f[3] = f2bf(w0.w);
            f[4] = f2bf(w1.x); f[5] = f2bf(w1.y); f[6] = f2bf(w1.z); f[7] = f2bf(w1.w);
            Bf[nt][ks] = f;
        }
    }
    float bias[4];
#pragma unroll
    for (int nt = 0; nt < 4; ++nt) bias[nt] = b[(size_t)t * D + nt * 16 + c];

    // ---- stage-0 x row (depends on aidx)
    float4 x0, x1, x2, x3;
    {
        const float4* xr = (const float4*)x + (size_t)aidx * 16 + q * 2;
        x0 = xr[0]; x1 = xr[1]; x2 = xr[8]; x3 = xr[9];
    }

    while (true) {
        const int gn = g + stride;
        const bool more = (gn * 16 < n);      // n uniform per block: no divergence

        // ---- prefetch next stage (issued before current compute)
        int naidx = 0; float4 nx0, nx1, nx2, nx3;
        if (more) {
            int ridx = gn * 16 + c;
            if (ridx >= n) ridx = n - 1;
            naidx = bk[ridx];
            const float4* xr = (const float4*)x + (size_t)naidx * 16 + q * 2;
            nx0 = xr[0]; nx1 = xr[1]; nx2 = xr[8]; nx3 = xr[9];
        }

        // ---- compute current group
        sfrag A0, A1;
        A0[0] = f2bf(x0.x); A0[1] = f2bf(x0.y); A0[2] = f2bf(x0.z); A0[3] = f2bf(x0.w);
        A0[4] = f2bf(x1.x); A0[5] = f2bf(x1.y); A0[6] = f2bf(x1.z); A0[7] = f2bf(x1.w);
        A1[0] = f2bf(x2.x); A1[1] = f2bf(x2.y); A1[2] = f2bf(x2.z); A1[3] = f2bf(x2.w);
        A1[4] = f2bf(x3.x); A1[5] = f2bf(x3.y); A1[6] = f2bf(x3.z); A1[7] = f2bf(x3.w);

        const int base = g * 16;
        int  oat[4]; bool ov[4];
#pragma unroll
        for (int r = 0; r < 4; ++r) {
            ov[r]  = (base + q * 4 + r) < n;
            oat[r] = __shfl(aidx, q * 4 + r, 64);   // lanes 0..15 hold bk[base+0..15]
        }

#pragma unroll
        for (int nt = 0; nt < 4; ++nt) {
            ffrag acc = {0.f, 0.f, 0.f, 0.f};
            acc = __builtin_amdgcn_mfma_f32_16x16x32_bf16(A0, Bf[nt][0], acc, 0, 0, 0);
            acc = __builtin_amdgcn_mfma_f32_16x16x32_bf16(A1, Bf[nt][1], acc, 0, 0, 0);
#pragma unroll
            for (int r = 0; r < 4; ++r) {
                if (ov[r])
                    out[(size_t)oat[r] * D + nt * 16 + c] = fast_tanh(acc[r] + bias[nt]);
            }
        }

        if (!more) break;
        g = gn; aidx = naidx;
        x0 = nx0; x1 = nx1; x2 = nx2; x3 = nx3;
    }
}

extern "C" void kernel_launch(void* const* d_in, const int* in_sizes, int n_in,
                              void* d_out, int out_size, void* d_ws, size_t ws_size,
                              hipStream_t stream)
{
    const float* x     = (const float*)d_in[0];
    const int*   types = (const int*)  d_in[1];
    const float* W     = (const float*)d_in[2];
    const float* b     = (const float*)d_in[3];
    float*       out   = (float*)d_out;

    int* cursor = (int*)d_ws;
    int* bucket = (int*)((char*)d_ws + 1024);

    hipMemsetAsync(cursor, 0, N_TYPES * sizeof(int), stream);
    scatter_kernel<<<dim3(N_ATOMS / 1024), dim3(256), 0, stream>>>(types, cursor, bucket);
    apply_kernel<<<dim3(BPT * N_TYPES), dim3(256), 0, stream>>>(x, W, b, bucket, cursor, out);
}